// Round 9
// baseline (252.258 us; speedup 1.0000x reference)
//
#include <hip/hip_runtime.h>

#define NN   40000
#define EE   640000
#define IND  5
#define ED   11
#define HIDD 128
#define F1   512       // 4 heads * 128
#define PSB  2500      // edge blocks -> psum rows

typedef unsigned short u16;
typedef unsigned int   u32;
typedef __attribute__((ext_vector_type(8))) short bf16x8;
typedef __attribute__((ext_vector_type(4))) float f32x4;

__device__ __forceinline__ float bf2f(u16 u) { return __uint_as_float(((u32)u) << 16); }
__device__ __forceinline__ u16 f2bf(float f) {
    u32 u = __float_as_uint(f);
    return (u16)((u + 0x7FFFu + ((u >> 16) & 1u)) >> 16);   // RNE
}

__device__ __forceinline__ float wsum(float v) {
#pragma unroll
    for (int o = 32; o; o >>= 1) v += __shfl_xor(v, o, 64);
    return v;
}
__device__ __forceinline__ float lrelu(float v) { return v > 0.f ? v : 0.2f * v; }

// edge record (16B, uint4): x=[e0|e1]bf16, y=[e2|e3]bf16, z=src, w=et2(f32 bits).
// tmp = record content in EDGE order (built in prep, hidden under atomics);
// build scatters tmp -> rec (dst-sorted). Self loops analytic (consts[80..83],[96]).
// gx: per-node 48B packed [aS1[0..3] | x[0..4] | pad3].
// consts layout (floats): [16..59] Be1[k*4+h], [64..74] Be2[k],
//   [80..83] self1[h], [96] self2

#define SBLK 256
#define SGRID ((NN + SBLK - 1) / SBLK)   // 157
#define PREPG (PSB + 33 + SGRID)         // edges(2500) + consts(1) + wswz(32) + gx(157)

// ---- prep: edge{count+rank+record+psum} | constsA | W2 swizzle | gx/aD1 ---------
__global__ void __launch_bounds__(256) k_prep(const int* __restrict__ ei,
                                              int* __restrict__ counts,
                                              int* __restrict__ rank,
                                              float* __restrict__ consts,
                                              const float* __restrict__ ea,
                                              float* __restrict__ psum,
                                              uint4* __restrict__ tmp,
                                              const float* __restrict__ We1,
                                              const float* __restrict__ ae1,
                                              const float* __restrict__ We2,
                                              const float* __restrict__ ae2,
                                              const float* __restrict__ W2,
                                              u16* __restrict__ bsw,
                                              const float* __restrict__ W1,
                                              const float* __restrict__ as1,
                                              const float* __restrict__ ad1,
                                              const float* __restrict__ x,
                                              float* __restrict__ gx,
                                              float* __restrict__ aD1) {
    int bid = blockIdx.x, t = threadIdx.x;
    if (bid < PSB) {   // edge role: atomic rank + full record content + ea psum
        __shared__ float shB[64];            // [0..43] Be1[k*4+h], [48..58] Be2[k]
        __shared__ float shf[4 * ED];
        int i = bid * 256 + t;
        int d = ei[EE + i];
        int rk = atomicAdd(&counts[d], 1);   // issue early; latency hides Be dots
        if (t < 44) {                        // block-redundant Be1 (bit-identical loop)
            int k = t >> 2, h = t & 3;
            float s = 0.f;
            for (int c = 0; c < HIDD; ++c)
                s += We1[k * F1 + h * HIDD + c] * ae1[h * HIDD + c];
            shB[t] = s;
        }
        if (t >= 48 && t < 48 + ED) {        // block-redundant Be2
            int k = t - 48;
            float s = 0.f;
            for (int c = 0; c < HIDD; ++c)
                s += We2[k * HIDD + c] * ae2[c];
            shB[t] = s;
        }
        __syncthreads();
        rank[i] = rk;
        const float* row = ea + (size_t)i * ED;
        float r[ED];
#pragma unroll
        for (int k = 0; k < ED; ++k) r[k] = row[k];
        float e0 = 0.f, e1 = 0.f, e2 = 0.f, e3 = 0.f, et = 0.f;
#pragma unroll
        for (int k = 0; k < ED; ++k) {
            float a = r[k];
            e0 += a * shB[k * 4 + 0];
            e1 += a * shB[k * 4 + 1];
            e2 += a * shB[k * 4 + 2];
            e3 += a * shB[k * 4 + 3];
            et += a * shB[48 + k];
        }
        uint4 q;
        q.x = (u32)f2bf(e0) | ((u32)f2bf(e1) << 16);
        q.y = (u32)f2bf(e2) | ((u32)f2bf(e3) << 16);
        q.z = (u32)ei[i];
        q.w = __float_as_uint(et);
        tmp[i] = q;
#pragma unroll
        for (int k = 0; k < ED; ++k) r[k] = wsum(r[k]);   // wave totals
        int wv = t >> 6, lane = t & 63;
#pragma unroll
        for (int k = 0; k < ED; ++k)
            if (lane == k) shf[wv * ED + k] = r[k];
        __syncthreads();
        if (t < ED)
            psum[(size_t)bid * ED + t] =
                shf[t] + shf[ED + t] + shf[2 * ED + t] + shf[3 * ED + t];
        return;
    }
    if (bid == PSB) {                        // Be1/Be2 -> consts (for sumred role)
        if (t < 44) {
            int k = t >> 2, h = t & 3;
            float s = 0.f;
            for (int c = 0; c < HIDD; ++c)
                s += We1[k * F1 + h * HIDD + c] * ae1[h * HIDD + c];
            consts[16 + t] = s;
        }
        if (t >= 48 && t < 48 + ED) {
            int k = t - 48;
            float s = 0.f;
            for (int c = 0; c < HIDD; ++c)
                s += We2[k * HIDD + c] * ae2[c];
            consts[64 + k] = s;
        }
        return;
    }
    if (bid < PSB + 33) {                    // W2 -> MFMA B-fragment order (bf16)
        int t2 = (bid - (PSB + 1)) * 256 + t;
        if (t2 >= 8192) return;
        int lane = t2 & 63, ks = (t2 >> 6) & 15, nt = t2 >> 10;
        int kbase = ks * 32 + (lane >> 4) * 8;
        int n = nt * 16 + (lane & 15);
        size_t dst = (size_t)t2 * 8;
#pragma unroll
        for (int j = 0; j < 8; ++j)
            bsw[dst + j] = f2bf(W2[(size_t)(kbase + j) * HIDD + n]);
        return;
    }
    // gx + aD1 role (block-redundant As/Ad dots)
    {
        __shared__ float sA[20], sD[20];
        if (t < 20) {                        // As[j][h] = sum_c W1[j,h*128+c]*as1[h,c]
            int j = t >> 2, h = t & 3;
            float s = 0.f;
            for (int c = 0; c < HIDD; ++c)
                s += W1[j * F1 + h * HIDD + c] * as1[h * HIDD + c];
            sA[t] = s;
        }
        if (t >= 32 && t < 52) {             // Ad[j][h]
            int u = t - 32, j = u >> 2, h = u & 3;
            float s = 0.f;
            for (int c = 0; c < HIDD; ++c)
                s += W1[j * F1 + h * HIDD + c] * ad1[h * HIDD + c];
            sD[u] = s;
        }
        __syncthreads();
        int n = (bid - (PSB + 33)) * 256 + t;
        if (n >= NN) return;
        const float* xp = x + (size_t)n * IND;
        float xv0 = xp[0], xv1 = xp[1], xv2 = xp[2], xv3 = xp[3], xv4 = xp[4];
        float4 s4, d4;
        float* sp = (float*)&s4;
        float* dp = (float*)&d4;
#pragma unroll
        for (int h = 0; h < 4; ++h) {
            sp[h] = xv0 * sA[0 * 4 + h] + xv1 * sA[1 * 4 + h] + xv2 * sA[2 * 4 + h]
                  + xv3 * sA[3 * 4 + h] + xv4 * sA[4 * 4 + h];
            dp[h] = xv0 * sD[0 * 4 + h] + xv1 * sD[1 * 4 + h] + xv2 * sD[2 * 4 + h]
                  + xv3 * sD[3 * 4 + h] + xv4 * sD[4 * 4 + h];
        }
        float* gp = gx + (size_t)n * 12;
        *(float4*)gp = s4;                   // [0..3]  aS1
        float4 xq; xq.x = xv0; xq.y = xv1; xq.z = xv2; xq.w = xv3;
        *(float4*)(gp + 4) = xq;             // [4..7]  x0..x3
        gp[8] = xv4;                         // [8]     x4
        *(float4*)(aD1 + (size_t)n * 4) = d4;
    }
}

// ---- scan (role A) | psum -> self consts (role B) -------------------------------
__global__ void __launch_bounds__(SBLK) k_scan(const int* __restrict__ counts,
                                               int* __restrict__ row_off,
                                               float* __restrict__ consts,
                                               const float* __restrict__ psum) {
    __shared__ int shi[SBLK];
    __shared__ float shf[4 * ED];
    __shared__ float mean[ED];
    __shared__ int s_boff;
    int t = threadIdx.x, b = blockIdx.x;
    if (b < SGRID) {                         // exclusive scan, redundant prefix
        int acc = 0;
        for (int i = t; i < b * SBLK; i += SBLK) acc += counts[i];
        shi[t] = acc;
        __syncthreads();
        for (int o = 128; o; o >>= 1) {
            if (t < o) shi[t] += shi[t + o];
            __syncthreads();
        }
        if (t == 0) s_boff = shi[0];
        __syncthreads();
        int boff = s_boff;
        __syncthreads();                     // shi reuse below
        int i = b * SBLK + t;
        int v = (i < NN) ? counts[i] : 0;
        shi[t] = v;
        __syncthreads();
        for (int o = 1; o < SBLK; o <<= 1) {
            int u = (t >= o) ? shi[t - o] : 0;
            __syncthreads();
            shi[t] += u;
            __syncthreads();
        }
        if (i < NN) row_off[i] = boff + shi[t] - v;
        if (b == 0 && t == 0) row_off[NN] = EE;
        return;
    }
    // sumred role: psum -> means -> self-loop consts
    float acc[ED];
#pragma unroll
    for (int k = 0; k < ED; ++k) acc[k] = 0.f;
    for (int w = t; w < PSB; w += SBLK) {
        const float* p = psum + (size_t)w * ED;
#pragma unroll
        for (int k = 0; k < ED; ++k) acc[k] += p[k];
    }
#pragma unroll
    for (int k = 0; k < ED; ++k) acc[k] = wsum(acc[k]);
    int wv = t >> 6, lane = t & 63;
#pragma unroll
    for (int k = 0; k < ED; ++k)
        if (lane == k) shf[wv * ED + k] = acc[k];
    __syncthreads();
    if (t < ED)
        mean[t] = (shf[t] + shf[ED + t] + shf[2 * ED + t] + shf[3 * ED + t])
                  * (1.0f / (float)EE);
    __syncthreads();
    if (t < 4) {
        float s = 0.f;
        for (int k = 0; k < ED; ++k) s += mean[k] * consts[16 + k * 4 + t];
        consts[80 + t] = s;
    }
    if (t == 8) {
        float s = 0.f;
        for (int k = 0; k < ED; ++k) s += mean[k] * consts[64 + k];
        consts[96] = s;
    }
}

// ---- build: thin scatter tmp -> rec ---------------------------------------------
__global__ void __launch_bounds__(256) k_build(const uint4* __restrict__ tmp,
                                               const int* __restrict__ ei,
                                               const int* __restrict__ rank,
                                               const int* __restrict__ row_off,
                                               uint4* __restrict__ rec) {
    int i = blockIdx.x * 256 + threadIdx.x;
    uint4 q = tmp[i];
    int d = ei[EE + i];
    rec[row_off[d] + rank[i]] = q;
}

// ---- layer 1 FUSED: score+softmax+agg -> h1 tile in LDS -> MFMA gemm2 -----------
__global__ void __launch_bounds__(256) k_agg1g(const int* __restrict__ row_off,
                                               const uint4* __restrict__ rec,
                                               const float* __restrict__ gx,
                                               const float* __restrict__ aD1,
                                               const float* __restrict__ W1,
                                               const float* __restrict__ b1,
                                               const float* __restrict__ consts,
                                               const u16* __restrict__ bsw,
                                               const float* __restrict__ as2,
                                               const float* __restrict__ ad2,
                                               u16* __restrict__ xh2,
                                               float* __restrict__ aS2,
                                               float* __restrict__ aD2) {
    __shared__ u16 hA[16 * 512];             // 16 KB, XOR-swizzled rows
    __shared__ float sh_ps[4][16], sh_pd[4][16];
    int wv = threadIdx.x >> 6, lane = threadIdx.x & 63;
    int g = lane >> 4, sl = lane & 15;
    int row = wv * 4 + g;
    int n0 = blockIdx.x * 16;
    int n = n0 + row;
    int s0 = row_off[n], s1 = row_off[n + 1];
    float4 adv = *(const float4*)(aD1 + (size_t)n * 4);   // uniform per 16-lane group
    float z0 = 0.f, z1 = 0.f, z2 = 0.f, z3 = 0.f;
    float xa[4][5];
#pragma unroll
    for (int h = 0; h < 4; ++h)
#pragma unroll
        for (int j = 0; j < 5; ++j) xa[h][j] = 0.f;

    int i = s0 + sl;
    uint4 q;
    if (i < s1) q = rec[i];
    while (i < s1) {
        int in2 = i + 16;
        uint4 qn;
        if (in2 < s1) qn = rec[in2];         // prefetch next rec (pipelined)
        int s = (int)q.z;
        const float* gp = gx + (size_t)s * 12;
        float4 as4 = *(const float4*)gp;
        float4 xq  = *(const float4*)(gp + 4);
        float x4v  = gp[8];
        float e0 = bf2f((u16)(q.x & 0xFFFF)), e1 = bf2f((u16)(q.x >> 16));
        float e2 = bf2f((u16)(q.y & 0xFFFF)), e3 = bf2f((u16)(q.y >> 16));
        float ex;
        ex = __expf(lrelu(e0 + as4.x + adv.x)); z0 += ex;
        xa[0][0] += ex * xq.x; xa[0][1] += ex * xq.y; xa[0][2] += ex * xq.z;
        xa[0][3] += ex * xq.w; xa[0][4] += ex * x4v;
        ex = __expf(lrelu(e1 + as4.y + adv.y)); z1 += ex;
        xa[1][0] += ex * xq.x; xa[1][1] += ex * xq.y; xa[1][2] += ex * xq.z;
        xa[1][3] += ex * xq.w; xa[1][4] += ex * x4v;
        ex = __expf(lrelu(e2 + as4.z + adv.z)); z2 += ex;
        xa[2][0] += ex * xq.x; xa[2][1] += ex * xq.y; xa[2][2] += ex * xq.z;
        xa[2][3] += ex * xq.w; xa[2][4] += ex * x4v;
        ex = __expf(lrelu(e3 + as4.w + adv.w)); z3 += ex;
        xa[3][0] += ex * xq.x; xa[3][1] += ex * xq.y; xa[3][2] += ex * xq.z;
        xa[3][3] += ex * xq.w; xa[3][4] += ex * x4v;
        i = in2; q = qn;
    }
    if (sl == 0) {   // analytic self loop (all 4 heads on one lane)
        const float* gp = gx + (size_t)n * 12;
        float4 as4 = *(const float4*)gp;
        float4 xq  = *(const float4*)(gp + 4);
        float x4v  = gp[8];
        float ex;
        ex = __expf(lrelu(consts[80] + as4.x + adv.x)); z0 += ex;
        xa[0][0] += ex * xq.x; xa[0][1] += ex * xq.y; xa[0][2] += ex * xq.z;
        xa[0][3] += ex * xq.w; xa[0][4] += ex * x4v;
        ex = __expf(lrelu(consts[81] + as4.y + adv.y)); z1 += ex;
        xa[1][0] += ex * xq.x; xa[1][1] += ex * xq.y; xa[1][2] += ex * xq.z;
        xa[1][3] += ex * xq.w; xa[1][4] += ex * x4v;
        ex = __expf(lrelu(consts[82] + as4.z + adv.z)); z2 += ex;
        xa[2][0] += ex * xq.x; xa[2][1] += ex * xq.y; xa[2][2] += ex * xq.z;
        xa[2][3] += ex * xq.w; xa[2][4] += ex * x4v;
        ex = __expf(lrelu(consts[83] + as4.w + adv.w)); z3 += ex;
        xa[3][0] += ex * xq.x; xa[3][1] += ex * xq.y; xa[3][2] += ex * xq.z;
        xa[3][3] += ex * xq.w; xa[3][4] += ex * x4v;
    }
#pragma unroll
    for (int o = 1; o <= 8; o <<= 1) {       // 16-lane butterfly
        z0 += __shfl_xor(z0, o, 64); z1 += __shfl_xor(z1, o, 64);
        z2 += __shfl_xor(z2, o, 64); z3 += __shfl_xor(z3, o, 64);
#pragma unroll
        for (int h = 0; h < 4; ++h)
#pragma unroll
            for (int j = 0; j < 5; ++j) xa[h][j] += __shfl_xor(xa[h][j], o, 64);
    }
    float zz[4] = {z0, z1, z2, z3};
    // h1 tile -> LDS (swizzled), relu(bias) applied, bf16 RNE
#pragma unroll
    for (int cb = 0; cb < 4; ++cb) {
        float ih = 1.f / (zz[cb] + 1e-16f);
        int c0 = cb * 128 + sl * 8;
        u32 wp[4];
#pragma unroll
        for (int jj = 0; jj < 4; ++jj) {
            int c = c0 + jj * 2;
            float v0 = (xa[cb][0] * W1[0 * F1 + c] + xa[cb][1] * W1[1 * F1 + c]
                      + xa[cb][2] * W1[2 * F1 + c] + xa[cb][3] * W1[3 * F1 + c]
                      + xa[cb][4] * W1[4 * F1 + c]) * ih;
            float v1 = (xa[cb][0] * W1[0 * F1 + c + 1] + xa[cb][1] * W1[1 * F1 + c + 1]
                      + xa[cb][2] * W1[2 * F1 + c + 1] + xa[cb][3] * W1[3 * F1 + c + 1]
                      + xa[cb][4] * W1[4 * F1 + c + 1]) * ih;
            v0 = fmaxf(v0 + b1[c], 0.f);
            v1 = fmaxf(v1 + b1[c + 1], 0.f);
            wp[jj] = (u32)f2bf(v0) | ((u32)f2bf(v1) << 16);
        }
        uint4 st; st.x = wp[0]; st.y = wp[1]; st.z = wp[2]; st.w = wp[3];
        int cbyte = (cb * 256 + sl * 16) ^ ((row & 7) << 4);
        *(uint4*)((char*)hA + row * 1024 + cbyte) = st;
    }
    __syncthreads();

    // ---- phase 2: MFMA tile. wave wv -> nt {2wv, 2wv+1} ----
    int mrow = lane & 15, quad = lane >> 4;
    const u16* bbase = bsw + lane * 8;
    int nt0 = wv * 2;
    f32x4 acc0 = (f32x4){0.f, 0.f, 0.f, 0.f};
    f32x4 acc1 = (f32x4){0.f, 0.f, 0.f, 0.f};
    const char* arow = (const char*)hA + mrow * 1024;
    int axor = (mrow & 7) << 4;
    bf16x8 af0 = *(const bf16x8*)(arow + ((quad * 16 + 0) ^ axor));
    bf16x8 af1;
    bf16x8 b00 = *(const bf16x8*)(bbase + (size_t)nt0 * 8192);
    bf16x8 b01 = *(const bf16x8*)(bbase + (size_t)(nt0 + 1) * 8192);
    bf16x8 n00, n01;
#pragma unroll
    for (int ks = 0; ks < 16; ++ks) {
        if (ks < 15) {
            af1 = *(const bf16x8*)(arow + ((quad * 16 + (ks + 1) * 64) ^ axor));
            n00 = *(const bf16x8*)(bbase + (size_t)nt0 * 8192 + (ks + 1) * 512);
            n01 = *(const bf16x8*)(bbase + (size_t)(nt0 + 1) * 8192 + (ks + 1) * 512);
        }
        acc0 = __builtin_amdgcn_mfma_f32_16x16x32_bf16(af0, b00, acc0, 0, 0, 0);
        acc1 = __builtin_amdgcn_mfma_f32_16x16x32_bf16(af0, b01, acc1, 0, 0, 0);
        af0 = af1; b00 = n00; b01 = n01;
    }
    // C layout: col = nt*16 + mrow, row = quad*4 + r
    float ps[4] = {0.f, 0.f, 0.f, 0.f}, pd[4] = {0.f, 0.f, 0.f, 0.f};
    {
        int col = nt0 * 16 + mrow;
        float sa = as2[col], da = ad2[col];
#pragma unroll
        for (int r = 0; r < 4; ++r) {
            float v = acc0[r];
            xh2[(size_t)(n0 + quad * 4 + r) * HIDD + col] = f2bf(v);
            ps[r] += v * sa; pd[r] += v * da;
        }
    }
    {
        int col = (nt0 + 1) * 16 + mrow;
        float sa = as2[col], da = ad2[col];
#pragma unroll
        for (int r = 0; r < 4; ++r) {
            float v = acc1[r];
            xh2[(size_t)(n0 + quad * 4 + r) * HIDD + col] = f2bf(v);
            ps[r] += v * sa; pd[r] += v * da;
        }
    }
#pragma unroll
    for (int r = 0; r < 4; ++r) {
#pragma unroll
        for (int o = 1; o <= 8; o <<= 1) {
            ps[r] += __shfl_xor(ps[r], o, 64);
            pd[r] += __shfl_xor(pd[r], o, 64);
        }
        if (mrow == 0) {
            sh_ps[wv][quad * 4 + r] = ps[r];
            sh_pd[wv][quad * 4 + r] = pd[r];
        }
    }
    __syncthreads();
    int t = threadIdx.x;
    if (t < 16) {
        float s = sh_ps[0][t] + sh_ps[1][t] + sh_ps[2][t] + sh_ps[3][t];
        aS2[n0 + t] = s;
    } else if (t < 32) {
        int r = t - 16;
        float s = sh_pd[0][r] + sh_pd[1][r] + sh_pd[2][r] + sh_pd[3][r];
        aD2[n0 + r] = s;
    }
}

// ---------------- layer 2: score+softmax+agg+FC+sigmoid, 4 nodes/block -----------
__global__ void __launch_bounds__(256) k_agg2(const int* __restrict__ row_off,
                                              const uint4* __restrict__ rec,
                                              const float* __restrict__ aS2,
                                              const float* __restrict__ aD2,
                                              const u16* __restrict__ xh2,
                                              const float* __restrict__ bias2,
                                              const float* __restrict__ Wfc,
                                              const float* __restrict__ bfc,
                                              const float* __restrict__ consts,
                                              float* __restrict__ out) {
    int n = blockIdx.x * 4 + (threadIdx.x >> 6);
    int t = threadIdx.x & 63;
    int s0 = row_off[n], s1 = row_off[n + 1];
    float adn = aD2[n];                      // uniform per wave
    int g = t >> 4, l = t & 15;
    int c0 = l * 8;
    float z = 0.f;
    float acc[8];
#pragma unroll
    for (int j = 0; j < 8; ++j) acc[j] = 0.f;
    int i = s0 + g;
    uint4 qe;
    if (i < s1) qe = rec[i];
    while (i < s1) {
        int in2 = i + 4;
        uint4 qn;
        if (in2 < s1) qn = rec[in2];         // prefetch next rec (pipelined)
        int s = (int)qe.z;
        float et2 = __uint_as_float(qe.w);
        float ex = __expf(lrelu(aS2[s] + adn + et2));
        z += ex;
        uint4 q = *(const uint4*)(xh2 + (size_t)s * HIDD + c0);   // 8 bf16
        acc[0] += ex * bf2f((u16)(q.x & 0xFFFF)); acc[1] += ex * bf2f((u16)(q.x >> 16));
        acc[2] += ex * bf2f((u16)(q.y & 0xFFFF)); acc[3] += ex * bf2f((u16)(q.y >> 16));
        acc[4] += ex * bf2f((u16)(q.z & 0xFFFF)); acc[5] += ex * bf2f((u16)(q.z >> 16));
        acc[6] += ex * bf2f((u16)(q.w & 0xFFFF)); acc[7] += ex * bf2f((u16)(q.w >> 16));
        i = in2; qe = qn;
    }
    if (g == 0) {   // analytic self loop, once per column-lane
        float ex = __expf(lrelu(aS2[n] + adn + consts[96]));
        z += ex;
        uint4 q = *(const uint4*)(xh2 + (size_t)n * HIDD + c0);
        acc[0] += ex * bf2f((u16)(q.x & 0xFFFF)); acc[1] += ex * bf2f((u16)(q.x >> 16));
        acc[2] += ex * bf2f((u16)(q.y & 0xFFFF)); acc[3] += ex * bf2f((u16)(q.y >> 16));
        acc[4] += ex * bf2f((u16)(q.z & 0xFFFF)); acc[5] += ex * bf2f((u16)(q.z >> 16));
        acc[6] += ex * bf2f((u16)(q.w & 0xFFFF)); acc[7] += ex * bf2f((u16)(q.w >> 16));
    }
#pragma unroll
    for (int o = 16; o <= 32; o <<= 1) {
        z += __shfl_xor(z, o, 64);
#pragma unroll
        for (int j = 0; j < 8; ++j) acc[j] += __shfl_xor(acc[j], o, 64);
    }
    float inv = 1.f / (z + 1e-16f);
    float p = 0.f;
#pragma unroll
    for (int j = 0; j < 8; ++j) {
        float o = fmaxf(acc[j] * inv + bias2[c0 + j], 0.f);
        p += o * Wfc[c0 + j];
    }
#pragma unroll
    for (int o = 1; o <= 8; o <<= 1) p += __shfl_xor(p, o, 64);
    if (t == 0) {
        float logit = p + bfc[0];
        out[n] = 1.f / (1.f + __expf(-logit));
    }
}

extern "C" void kernel_launch(void* const* d_in, const int* in_sizes, int n_in,
                              void* d_out, int out_size, void* d_ws, size_t ws_size,
                              hipStream_t stream) {
    (void)in_sizes; (void)n_in; (void)out_size; (void)ws_size;
    const float* x   = (const float*)d_in[0];
    const int*   ei  = (const int*)d_in[1];
    const float* ea  = (const float*)d_in[2];
    const float* W1  = (const float*)d_in[3];
    const float* We1 = (const float*)d_in[4];
    const float* as1 = (const float*)d_in[5];
    const float* ad1 = (const float*)d_in[6];
    const float* ae1 = (const float*)d_in[7];
    const float* b1  = (const float*)d_in[8];
    const float* W2  = (const float*)d_in[9];
    const float* We2 = (const float*)d_in[10];
    const float* as2 = (const float*)d_in[11];
    const float* ad2 = (const float*)d_in[12];
    const float* ae2 = (const float*)d_in[13];
    const float* b2v = (const float*)d_in[14];
    const float* Wfc = (const float*)d_in[15];
    const float* bfc = (const float*)d_in[16];
    float* out = (float*)d_out;

    char* ws = (char*)d_ws;
    size_t off = 0;
    auto take = [&](size_t nb) {
        size_t r = off;
        off += (nb + 255) & ~(size_t)255;
        return r;
    };
    // memset region: consts | counts (contiguous, zeroed in one go)
    float* consts = (float*)(ws + take(1024));
    int*   counts = (int*)(ws + take((size_t)NN * 4));
    size_t zbytes = off;
    int* row_off  = (int*)(ws + take((size_t)(NN + 1) * 4));
    int* rank     = (int*)(ws + take((size_t)EE * 4));
    float* psum   = (float*)(ws + take((size_t)PSB * ED * 4));
    uint4* tmp    = (uint4*)(ws + take((size_t)EE * 16));
    uint4* rec    = (uint4*)(ws + take((size_t)EE * 16));
    float* gx     = (float*)(ws + take((size_t)NN * 48));
    float* aD1    = (float*)(ws + take((size_t)NN * 16));
    float* aS2    = (float*)(ws + take((size_t)NN * 4));
    float* aD2    = (float*)(ws + take((size_t)NN * 4));
    u16* xh2      = (u16*)(ws + take((size_t)NN * HIDD * 2));
    u16* w2b      = (u16*)(ws + take((size_t)65536 * 2));

    hipMemsetAsync(ws, 0, zbytes, stream);
    k_prep<<<PREPG, 256, 0, stream>>>(ei, counts, rank, consts, ea, psum, tmp,
                                      We1, ae1, We2, ae2, W2, w2b, W1, as1, ad1,
                                      x, gx, aD1);
    k_scan<<<SGRID + 1, SBLK, 0, stream>>>(counts, row_off, consts, psum);
    k_build<<<PSB, 256, 0, stream>>>(tmp, ei, rank, row_off, rec);
    k_agg1g<<<PSB, 256, 0, stream>>>(row_off, rec, gx, aD1, W1, b1, consts,
                                     w2b, as2, ad2, xh2, aS2, aD2);
    k_agg2<<<NN / 4, 256, 0, stream>>>(row_off, rec, aS2, aD2, xh2, b2v, Wfc, bfc,
                                       consts, out);
}

// Round 10
// 233.373 us; speedup vs baseline: 1.0809x; 1.0809x over previous
//
#include <hip/hip_runtime.h>

#define NN   40000
#define EE   640000
#define IND  5
#define ED   11
#define HIDD 128
#define F1   512       // 4 heads * 128
#define EB   1250      // edge blocks (2 edges/thread)

typedef unsigned short u16;
typedef unsigned int   u32;
typedef __attribute__((ext_vector_type(8))) short bf16x8;
typedef __attribute__((ext_vector_type(4))) float f32x4;

__device__ __forceinline__ float bf2f(u16 u) { return __uint_as_float(((u32)u) << 16); }
__device__ __forceinline__ u16 f2bf(float f) {
    u32 u = __float_as_uint(f);
    return (u16)((u + 0x7FFFu + ((u >> 16) & 1u)) >> 16);   // RNE
}

__device__ __forceinline__ float wsum(float v) {
#pragma unroll
    for (int o = 32; o; o >>= 1) v += __shfl_xor(v, o, 64);
    return v;
}
__device__ __forceinline__ float lrelu(float v) { return v > 0.f ? v : 0.2f * v; }

// edge record (16B, uint4): x=[e0|e1]bf16, y=[e2|e3]bf16, z=src, w=et2(f32 bits).
// dst implicit (records dst-sorted). Self loops analytic via consts[80..83],[96].
// consts layout (floats): [16..59] Be1[k*4+h], [64..74] Be2[k],
//   [80..83] self1[h], [96] self2, [100..119] As[j*4+h], [120..139] Ad[j*4+h]

#define SBLK 256
#define SGRID ((NN + SBLK - 1) / SBLK)   // 157
#define PREPG (EB + 33)                  // edges(1250) + consts(1) + wswz(32)

// ---- prep: count+rank+ea-psum (2 edges/thread) | constsA | W2 swizzle -----------
__global__ void __launch_bounds__(256) k_prep(const int* __restrict__ ei,
                                              int* __restrict__ counts,
                                              int* __restrict__ rank,
                                              float* __restrict__ consts,
                                              const float* __restrict__ ea,
                                              float* __restrict__ psum,
                                              const float* __restrict__ We1,
                                              const float* __restrict__ ae1,
                                              const float* __restrict__ We2,
                                              const float* __restrict__ ae2,
                                              const float* __restrict__ W2,
                                              u16* __restrict__ bsw,
                                              const float* __restrict__ W1,
                                              const float* __restrict__ as1,
                                              const float* __restrict__ ad1) {
    __shared__ float shf[4 * ED];
    int bid = blockIdx.x, t = threadIdx.x;
    if (bid < EB) {        // 512 edges/block: two independent atomic+sum chains
        int i0 = bid * 512 + t;
        int i1 = i0 + 256;
        int d0 = ei[EE + i0];
        int d1 = ei[EE + i1];
        int rk0 = atomicAdd(&counts[d0], 1);
        int rk1 = atomicAdd(&counts[d1], 1);
        rank[i0] = rk0;
        rank[i1] = rk1;
        const float* r0 = ea + (size_t)i0 * ED;
        const float* r1 = ea + (size_t)i1 * ED;
        float r[ED];
#pragma unroll
        for (int k = 0; k < ED; ++k) r[k] = r0[k] + r1[k];
#pragma unroll
        for (int k = 0; k < ED; ++k) r[k] = wsum(r[k]);   // wave totals, all lanes
        int wv = t >> 6, lane = t & 63;
#pragma unroll
        for (int k = 0; k < ED; ++k)
            if (lane == k) shf[wv * ED + k] = r[k];
        __syncthreads();
        if (t < ED)
            psum[(size_t)bid * ED + t] =
                shf[t] + shf[ED + t] + shf[2 * ED + t] + shf[3 * ED + t];
        return;
    }
    if (bid == EB) {                         // const dots
        if (t < 44) {
            int k = t >> 2, h = t & 3;
            float s = 0.f;
            for (int c = 0; c < HIDD; ++c)
                s += We1[k * F1 + h * HIDD + c] * ae1[h * HIDD + c];
            consts[16 + t] = s;
        }
        if (t >= 48 && t < 48 + ED) {
            int k = t - 48;
            float s = 0.f;
            for (int c = 0; c < HIDD; ++c)
                s += We2[k * HIDD + c] * ae2[c];
            consts[64 + k] = s;
        }
        if (t >= 64 && t < 84) {             // As[j][h] = sum_c W1[j,h*128+c]*as1[h,c]
            int idx = t - 64, j = idx >> 2, h = idx & 3;
            float s = 0.f;
            for (int c = 0; c < HIDD; ++c)
                s += W1[j * F1 + h * HIDD + c] * as1[h * HIDD + c];
            consts[100 + idx] = s;
        }
        if (t >= 84 && t < 104) {            // Ad[j][h]
            int idx = t - 84, j = idx >> 2, h = idx & 3;
            float s = 0.f;
            for (int c = 0; c < HIDD; ++c)
                s += W1[j * F1 + h * HIDD + c] * ad1[h * HIDD + c];
            consts[120 + idx] = s;
        }
        return;
    }
    // W2 -> MFMA B-fragment order (bf16)
    int t2 = (bid - (EB + 1)) * 256 + t;
    if (t2 >= 8192) return;
    int lane = t2 & 63, ks = (t2 >> 6) & 15, nt = t2 >> 10;
    int kbase = ks * 32 + (lane >> 4) * 8;
    int n = nt * 16 + (lane & 15);
    size_t dst = (size_t)t2 * 8;
#pragma unroll
    for (int j = 0; j < 8; ++j)
        bsw[dst + j] = f2bf(W2[(size_t)(kbase + j) * HIDD + n]);
}

// ---- scan (role A) | aS1/aD1 via As/Ad (role B) | psum->self consts (role C) ----
__global__ void __launch_bounds__(SBLK) k_scan(const int* __restrict__ counts,
                                               int* __restrict__ row_off,
                                               const float* __restrict__ x,
                                               float* __restrict__ consts,
                                               float* __restrict__ aS1,
                                               float* __restrict__ aD1,
                                               const float* __restrict__ psum) {
    __shared__ int shi[SBLK];
    __shared__ float shf[4 * ED];
    __shared__ float mean[ED];
    __shared__ int s_boff;
    int t = threadIdx.x, b = blockIdx.x;
    if (b < SGRID) {                         // exclusive scan, redundant prefix
        int acc = 0;
        for (int i = t; i < b * SBLK; i += SBLK) acc += counts[i];
        shi[t] = acc;
        __syncthreads();
        for (int o = 128; o; o >>= 1) {
            if (t < o) shi[t] += shi[t + o];
            __syncthreads();
        }
        if (t == 0) s_boff = shi[0];
        __syncthreads();
        int boff = s_boff;
        __syncthreads();                     // shi reuse below
        int i = b * SBLK + t;
        int v = (i < NN) ? counts[i] : 0;
        shi[t] = v;
        __syncthreads();
        for (int o = 1; o < SBLK; o <<= 1) {
            int u = (t >= o) ? shi[t - o] : 0;
            __syncthreads();
            shi[t] += u;
            __syncthreads();
        }
        if (i < NN) row_off[i] = boff + shi[t] - v;
        if (b == 0 && t == 0) row_off[NN] = EE;
        return;
    }
    if (b == SGRID * 2) {                    // sumred role: psum -> self consts
        float acc[ED];
#pragma unroll
        for (int k = 0; k < ED; ++k) acc[k] = 0.f;
        for (int w = t; w < EB; w += SBLK) {
            const float* p = psum + (size_t)w * ED;
#pragma unroll
            for (int k = 0; k < ED; ++k) acc[k] += p[k];
        }
#pragma unroll
        for (int k = 0; k < ED; ++k) acc[k] = wsum(acc[k]);
        int wv = t >> 6, lane = t & 63;
#pragma unroll
        for (int k = 0; k < ED; ++k)
            if (lane == k) shf[wv * ED + k] = acc[k];
        __syncthreads();
        if (t < ED)
            mean[t] = (shf[t] + shf[ED + t] + shf[2 * ED + t] + shf[3 * ED + t])
                      * (1.0f / (float)EE);
        __syncthreads();
        if (t < 4) {
            float s = 0.f;
            for (int k = 0; k < ED; ++k) s += mean[k] * consts[16 + k * 4 + t];
            consts[80 + t] = s;
        }
        if (t == 8) {
            float s = 0.f;
            for (int k = 0; k < ED; ++k) s += mean[k] * consts[64 + k];
            consts[96] = s;
        }
        return;
    }
    int n = (b - SGRID) * SBLK + t;          // aS1/aD1 role
    if (n >= NN) return;
    const float* xp = x + (size_t)n * IND;
    float xv0 = xp[0], xv1 = xp[1], xv2 = xp[2], xv3 = xp[3], xv4 = xp[4];
    float4 s4, d4;
    float* sp = (float*)&s4;
    float* dp = (float*)&d4;
#pragma unroll
    for (int h = 0; h < 4; ++h) {
        sp[h] = xv0 * consts[100 + 0 * 4 + h] + xv1 * consts[100 + 1 * 4 + h]
              + xv2 * consts[100 + 2 * 4 + h] + xv3 * consts[100 + 3 * 4 + h]
              + xv4 * consts[100 + 4 * 4 + h];
        dp[h] = xv0 * consts[120 + 0 * 4 + h] + xv1 * consts[120 + 1 * 4 + h]
              + xv2 * consts[120 + 2 * 4 + h] + xv3 * consts[120 + 3 * 4 + h]
              + xv4 * consts[120 + 4 * 4 + h];
    }
    *(float4*)(aS1 + (size_t)n * 4) = s4;
    *(float4*)(aD1 + (size_t)n * 4) = d4;
}

// ---- build records (2 edges/thread, two independent scatter chains) -------------
__global__ void __launch_bounds__(256) k_build(const float* __restrict__ ea,
                                               const int* __restrict__ ei,
                                               const int* __restrict__ rank,
                                               const int* __restrict__ row_off,
                                               const float* __restrict__ consts,
                                               uint4* __restrict__ rec) {
    int t = threadIdx.x;
    int i0 = blockIdx.x * 512 + t;
    int i1 = i0 + 256;
    int s0v = ei[i0], s1v = ei[i1];
    int d0 = ei[EE + i0], d1 = ei[EE + i1];
    int p0 = row_off[d0] + rank[i0];
    int p1 = row_off[d1] + rank[i1];
    const float* r0 = ea + (size_t)i0 * ED;
    const float* r1 = ea + (size_t)i1 * ED;
    float a0 = 0.f, a1 = 0.f, a2 = 0.f, a3 = 0.f, a4 = 0.f;
    float b0 = 0.f, b1 = 0.f, b2 = 0.f, b3 = 0.f, b4 = 0.f;
#pragma unroll
    for (int k = 0; k < ED; ++k) {
        float c0 = consts[16 + k * 4 + 0], c1 = consts[16 + k * 4 + 1];
        float c2 = consts[16 + k * 4 + 2], c3 = consts[16 + k * 4 + 3];
        float ct = consts[64 + k];
        float v0 = r0[k], v1 = r1[k];
        a0 += v0 * c0; a1 += v0 * c1; a2 += v0 * c2; a3 += v0 * c3; a4 += v0 * ct;
        b0 += v1 * c0; b1 += v1 * c1; b2 += v1 * c2; b3 += v1 * c3; b4 += v1 * ct;
    }
    uint4 q0, q1;
    q0.x = (u32)f2bf(a0) | ((u32)f2bf(a1) << 16);
    q0.y = (u32)f2bf(a2) | ((u32)f2bf(a3) << 16);
    q0.z = (u32)s0v;
    q0.w = __float_as_uint(a4);
    q1.x = (u32)f2bf(b0) | ((u32)f2bf(b1) << 16);
    q1.y = (u32)f2bf(b2) | ((u32)f2bf(b3) << 16);
    q1.z = (u32)s1v;
    q1.w = __float_as_uint(b4);
    rec[p0] = q0;
    rec[p1] = q1;
}

// ---- layer 1 FUSED: score+softmax+agg -> h1 tile in LDS -> MFMA gemm2 -----------
// Block = 16 nodes = one 16x512 @ 512x128 tile. Phase 1: 4 nodes/wave, lane/edge.
// Phase 2: wave wv handles nt = {2wv, 2wv+1}; A from swizzled LDS, B from L2.
__global__ void __launch_bounds__(256) k_agg1g(const int* __restrict__ row_off,
                                               const uint4* __restrict__ rec,
                                               const float* __restrict__ aS1,
                                               const float* __restrict__ aD1,
                                               const float* __restrict__ x,
                                               const float* __restrict__ W1,
                                               const float* __restrict__ b1,
                                               const float* __restrict__ consts,
                                               const u16* __restrict__ bsw,
                                               const float* __restrict__ as2,
                                               const float* __restrict__ ad2,
                                               u16* __restrict__ xh2,
                                               float* __restrict__ aS2,
                                               float* __restrict__ aD2) {
    __shared__ u16 hA[16 * 512];             // 16 KB, XOR-swizzled rows
    __shared__ float sh_ps[4][16], sh_pd[4][16];
    int wv = threadIdx.x >> 6, lane = threadIdx.x & 63;
    int g = lane >> 4, sl = lane & 15;
    int row = wv * 4 + g;
    int n0 = blockIdx.x * 16;
    int n = n0 + row;
    int s0 = row_off[n], s1 = row_off[n + 1];
    float4 adv = *(const float4*)(aD1 + (size_t)n * 4);   // uniform per 16-lane group
    float z0 = 0.f, z1 = 0.f, z2 = 0.f, z3 = 0.f;
    float xa[4][5];
#pragma unroll
    for (int h = 0; h < 4; ++h)
#pragma unroll
        for (int j = 0; j < 5; ++j) xa[h][j] = 0.f;

    for (int i = s0 + sl; i < s1; i += 16) {
        uint4 q = rec[i];
        int s = (int)q.z;
        float e0 = bf2f((u16)(q.x & 0xFFFF)), e1 = bf2f((u16)(q.x >> 16));
        float e2 = bf2f((u16)(q.y & 0xFFFF)), e3 = bf2f((u16)(q.y >> 16));
        float4 as4 = *(const float4*)(aS1 + (size_t)s * 4);
        const float* xp = x + (size_t)s * IND;
        float x0 = xp[0], x1 = xp[1], x2 = xp[2], x3 = xp[3], x4 = xp[4];
        float ex;
        ex = __expf(lrelu(e0 + as4.x + adv.x)); z0 += ex;
        xa[0][0] += ex * x0; xa[0][1] += ex * x1; xa[0][2] += ex * x2;
        xa[0][3] += ex * x3; xa[0][4] += ex * x4;
        ex = __expf(lrelu(e1 + as4.y + adv.y)); z1 += ex;
        xa[1][0] += ex * x0; xa[1][1] += ex * x1; xa[1][2] += ex * x2;
        xa[1][3] += ex * x3; xa[1][4] += ex * x4;
        ex = __expf(lrelu(e2 + as4.z + adv.z)); z2 += ex;
        xa[2][0] += ex * x0; xa[2][1] += ex * x1; xa[2][2] += ex * x2;
        xa[2][3] += ex * x3; xa[2][4] += ex * x4;
        ex = __expf(lrelu(e3 + as4.w + adv.w)); z3 += ex;
        xa[3][0] += ex * x0; xa[3][1] += ex * x1; xa[3][2] += ex * x2;
        xa[3][3] += ex * x3; xa[3][4] += ex * x4;
    }
    if (sl == 0) {   // analytic self loop (all 4 heads on one lane)
        float4 as4 = *(const float4*)(aS1 + (size_t)n * 4);
        const float* xp = x + (size_t)n * IND;
        float x0 = xp[0], x1 = xp[1], x2 = xp[2], x3 = xp[3], x4 = xp[4];
        float ex;
        ex = __expf(lrelu(consts[80] + as4.x + adv.x)); z0 += ex;
        xa[0][0] += ex * x0; xa[0][1] += ex * x1; xa[0][2] += ex * x2;
        xa[0][3] += ex * x3; xa[0][4] += ex * x4;
        ex = __expf(lrelu(consts[81] + as4.y + adv.y)); z1 += ex;
        xa[1][0] += ex * x0; xa[1][1] += ex * x1; xa[1][2] += ex * x2;
        xa[1][3] += ex * x3; xa[1][4] += ex * x4;
        ex = __expf(lrelu(consts[82] + as4.z + adv.z)); z2 += ex;
        xa[2][0] += ex * x0; xa[2][1] += ex * x1; xa[2][2] += ex * x2;
        xa[2][3] += ex * x3; xa[2][4] += ex * x4;
        ex = __expf(lrelu(consts[83] + as4.w + adv.w)); z3 += ex;
        xa[3][0] += ex * x0; xa[3][1] += ex * x1; xa[3][2] += ex * x2;
        xa[3][3] += ex * x3; xa[3][4] += ex * x4;
    }
#pragma unroll
    for (int o = 1; o <= 8; o <<= 1) {       // 16-lane butterfly
        z0 += __shfl_xor(z0, o, 64); z1 += __shfl_xor(z1, o, 64);
        z2 += __shfl_xor(z2, o, 64); z3 += __shfl_xor(z3, o, 64);
#pragma unroll
        for (int h = 0; h < 4; ++h)
#pragma unroll
            for (int j = 0; j < 5; ++j) xa[h][j] += __shfl_xor(xa[h][j], o, 64);
    }
    float zz[4] = {z0, z1, z2, z3};
    // h1 tile -> LDS (swizzled), relu(bias) applied, bf16 RNE
#pragma unroll
    for (int cb = 0; cb < 4; ++cb) {
        float ih = 1.f / (zz[cb] + 1e-16f);
        int c0 = cb * 128 + sl * 8;
        u32 wp[4];
#pragma unroll
        for (int jj = 0; jj < 4; ++jj) {
            int c = c0 + jj * 2;
            float v0 = (xa[cb][0] * W1[0 * F1 + c] + xa[cb][1] * W1[1 * F1 + c]
                      + xa[cb][2] * W1[2 * F1 + c] + xa[cb][3] * W1[3 * F1 + c]
                      + xa[cb][4] * W1[4 * F1 + c]) * ih;
            float v1 = (xa[cb][0] * W1[0 * F1 + c + 1] + xa[cb][1] * W1[1 * F1 + c + 1]
                      + xa[cb][2] * W1[2 * F1 + c + 1] + xa[cb][3] * W1[3 * F1 + c + 1]
                      + xa[cb][4] * W1[4 * F1 + c + 1]) * ih;
            v0 = fmaxf(v0 + b1[c], 0.f);
            v1 = fmaxf(v1 + b1[c + 1], 0.f);
            wp[jj] = (u32)f2bf(v0) | ((u32)f2bf(v1) << 16);
        }
        uint4 st; st.x = wp[0]; st.y = wp[1]; st.z = wp[2]; st.w = wp[3];
        int cbyte = (cb * 256 + sl * 16) ^ ((row & 7) << 4);
        *(uint4*)((char*)hA + row * 1024 + cbyte) = st;
    }
    __syncthreads();

    // ---- phase 2: MFMA tile. wave wv -> nt {2wv, 2wv+1} ----
    int mrow = lane & 15, quad = lane >> 4;
    const u16* bbase = bsw + lane * 8;
    int nt0 = wv * 2;
    f32x4 acc0 = (f32x4){0.f, 0.f, 0.f, 0.f};
    f32x4 acc1 = (f32x4){0.f, 0.f, 0.f, 0.f};
    const char* arow = (const char*)hA + mrow * 1024;
    int axor = (mrow & 7) << 4;
    bf16x8 af0 = *(const bf16x8*)(arow + ((quad * 16 + 0) ^ axor));
    bf16x8 af1;
    bf16x8 b00 = *(const bf16x8*)(bbase + (size_t)nt0 * 8192);
    bf16x8 b01 = *(const bf16x8*)(bbase + (size_t)(nt0 + 1) * 8192);
    bf16x8 n00, n01;
#pragma unroll
    for (int ks = 0; ks < 16; ++ks) {
        if (ks < 15) {
            af1 = *(const bf16x8*)(arow + ((quad * 16 + (ks + 1) * 64) ^ axor));
            n00 = *(const bf16x8*)(bbase + (size_t)nt0 * 8192 + (ks + 1) * 512);
            n01 = *(const bf16x8*)(bbase + (size_t)(nt0 + 1) * 8192 + (ks + 1) * 512);
        }
        acc0 = __builtin_amdgcn_mfma_f32_16x16x32_bf16(af0, b00, acc0, 0, 0, 0);
        acc1 = __builtin_amdgcn_mfma_f32_16x16x32_bf16(af0, b01, acc1, 0, 0, 0);
        af0 = af1; b00 = n00; b01 = n01;
    }
    // C layout: col = nt*16 + mrow, row = quad*4 + r
    float ps[4] = {0.f, 0.f, 0.f, 0.f}, pd[4] = {0.f, 0.f, 0.f, 0.f};
    {
        int col = nt0 * 16 + mrow;
        float sa = as2[col], da = ad2[col];
#pragma unroll
        for (int r = 0; r < 4; ++r) {
            float v = acc0[r];
            xh2[(size_t)(n0 + quad * 4 + r) * HIDD + col] = f2bf(v);
            ps[r] += v * sa; pd[r] += v * da;
        }
    }
    {
        int col = (nt0 + 1) * 16 + mrow;
        float sa = as2[col], da = ad2[col];
#pragma unroll
        for (int r = 0; r < 4; ++r) {
            float v = acc1[r];
            xh2[(size_t)(n0 + quad * 4 + r) * HIDD + col] = f2bf(v);
            ps[r] += v * sa; pd[r] += v * da;
        }
    }
#pragma unroll
    for (int r = 0; r < 4; ++r) {
#pragma unroll
        for (int o = 1; o <= 8; o <<= 1) {
            ps[r] += __shfl_xor(ps[r], o, 64);
            pd[r] += __shfl_xor(pd[r], o, 64);
        }
        if (mrow == 0) {
            sh_ps[wv][quad * 4 + r] = ps[r];
            sh_pd[wv][quad * 4 + r] = pd[r];
        }
    }
    __syncthreads();
    int t = threadIdx.x;
    if (t < 16) {
        float s = sh_ps[0][t] + sh_ps[1][t] + sh_ps[2][t] + sh_ps[3][t];
        aS2[n0 + t] = s;
    } else if (t < 32) {
        int r = t - 16;
        float s = sh_pd[0][r] + sh_pd[1][r] + sh_pd[2][r] + sh_pd[3][r];
        aD2[n0 + r] = s;
    }
}

// ---------------- layer 2: score+softmax+agg+FC+sigmoid, 4 nodes/block -----------
__global__ void __launch_bounds__(256) k_agg2(const int* __restrict__ row_off,
                                              const uint4* __restrict__ rec,
                                              const float* __restrict__ aS2,
                                              const float* __restrict__ aD2,
                                              const u16* __restrict__ xh2,
                                              const float* __restrict__ bias2,
                                              const float* __restrict__ Wfc,
                                              const float* __restrict__ bfc,
                                              const float* __restrict__ consts,
                                              float* __restrict__ out) {
    int n = blockIdx.x * 4 + (threadIdx.x >> 6);
    int t = threadIdx.x & 63;
    int s0 = row_off[n], s1 = row_off[n + 1];
    float adn = aD2[n];                      // uniform per wave
    int g = t >> 4, l = t & 15;
    int c0 = l * 8;
    float z = 0.f;
    float acc[8];
#pragma unroll
    for (int j = 0; j < 8; ++j) acc[j] = 0.f;
    for (int i = s0 + g; i < s1; i += 4) {
        uint4 qe = rec[i];
        int s = (int)qe.z;
        float et2 = __uint_as_float(qe.w);
        float ex = __expf(lrelu(aS2[s] + adn + et2));
        z += ex;
        uint4 q = *(const uint4*)(xh2 + (size_t)s * HIDD + c0);   // 8 bf16
        acc[0] += ex * bf2f((u16)(q.x & 0xFFFF)); acc[1] += ex * bf2f((u16)(q.x >> 16));
        acc[2] += ex * bf2f((u16)(q.y & 0xFFFF)); acc[3] += ex * bf2f((u16)(q.y >> 16));
        acc[4] += ex * bf2f((u16)(q.z & 0xFFFF)); acc[5] += ex * bf2f((u16)(q.z >> 16));
        acc[6] += ex * bf2f((u16)(q.w & 0xFFFF)); acc[7] += ex * bf2f((u16)(q.w >> 16));
    }
    if (g == 0) {   // analytic self loop, once per column-lane
        float ex = __expf(lrelu(aS2[n] + adn + consts[96]));
        z += ex;
        uint4 q = *(const uint4*)(xh2 + (size_t)n * HIDD + c0);
        acc[0] += ex * bf2f((u16)(q.x & 0xFFFF)); acc[1] += ex * bf2f((u16)(q.x >> 16));
        acc[2] += ex * bf2f((u16)(q.y & 0xFFFF)); acc[3] += ex * bf2f((u16)(q.y >> 16));
        acc[4] += ex * bf2f((u16)(q.z & 0xFFFF)); acc[5] += ex * bf2f((u16)(q.z >> 16));
        acc[6] += ex * bf2f((u16)(q.w & 0xFFFF)); acc[7] += ex * bf2f((u16)(q.w >> 16));
    }
#pragma unroll
    for (int o = 16; o <= 32; o <<= 1) {
        z += __shfl_xor(z, o, 64);
#pragma unroll
        for (int j = 0; j < 8; ++j) acc[j] += __shfl_xor(acc[j], o, 64);
    }
    float inv = 1.f / (z + 1e-16f);
    float p = 0.f;
#pragma unroll
    for (int j = 0; j < 8; ++j) {
        float o = fmaxf(acc[j] * inv + bias2[c0 + j], 0.f);
        p += o * Wfc[c0 + j];
    }
#pragma unroll
    for (int o = 1; o <= 8; o <<= 1) p += __shfl_xor(p, o, 64);
    if (t == 0) {
        float logit = p + bfc[0];
        out[n] = 1.f / (1.f + __expf(-logit));
    }
}

extern "C" void kernel_launch(void* const* d_in, const int* in_sizes, int n_in,
                              void* d_out, int out_size, void* d_ws, size_t ws_size,
                              hipStream_t stream) {
    (void)in_sizes; (void)n_in; (void)out_size; (void)ws_size;
    const float* x   = (const float*)d_in[0];
    const int*   ei  = (const int*)d_in[1];
    const float* ea  = (const float*)d_in[2];
    const float* W1  = (const float*)d_in[3];
    const float* We1 = (const float*)d_in[4];
    const float* as1 = (const float*)d_in[5];
    const float* ad1 = (const float*)d_in[6];
    const float* ae1 = (const float*)d_in[7];
    const float* b1  = (const float*)d_in[8];
    const float* W2  = (const float*)d_in[9];
    const float* We2 = (const float*)d_in[10];
    const float* as2 = (const float*)d_in[11];
    const float* ad2 = (const float*)d_in[12];
    const float* ae2 = (const float*)d_in[13];
    const float* b2v = (const float*)d_in[14];
    const float* Wfc = (const float*)d_in[15];
    const float* bfc = (const float*)d_in[16];
    float* out = (float*)d_out;

    char* ws = (char*)d_ws;
    size_t off = 0;
    auto take = [&](size_t nb) {
        size_t r = off;
        off += (nb + 255) & ~(size_t)255;
        return r;
    };
    // memset region: consts | counts (contiguous, zeroed in one go)
    float* consts = (float*)(ws + take(1024));
    int*   counts = (int*)(ws + take((size_t)NN * 4));
    size_t zbytes = off;
    int* row_off  = (int*)(ws + take((size_t)(NN + 1) * 4));
    int* rank     = (int*)(ws + take((size_t)EE * 4));
    float* psum   = (float*)(ws + take((size_t)EB * ED * 4));
    uint4* rec    = (uint4*)(ws + take((size_t)EE * 16));
    float* aS1    = (float*)(ws + take((size_t)NN * 16));
    float* aD1    = (float*)(ws + take((size_t)NN * 16));
    float* aS2    = (float*)(ws + take((size_t)NN * 4));
    float* aD2    = (float*)(ws + take((size_t)NN * 4));
    u16* xh2      = (u16*)(ws + take((size_t)NN * HIDD * 2));
    u16* w2b      = (u16*)(ws + take((size_t)65536 * 2));

    hipMemsetAsync(ws, 0, zbytes, stream);
    k_prep<<<PREPG, 256, 0, stream>>>(ei, counts, rank, consts, ea, psum,
                                      We1, ae1, We2, ae2, W2, w2b, W1, as1, ad1);
    k_scan<<<SGRID * 2 + 1, SBLK, 0, stream>>>(counts, row_off, x, consts,
                                               aS1, aD1, psum);
    k_build<<<EB, 256, 0, stream>>>(ea, ei, rank, row_off, consts, rec);
    k_agg1g<<<2500, 256, 0, stream>>>(row_off, rec, aS1, aD1, x, W1, b1, consts,
                                      w2b, as2, ad2, xh2, aS2, aD2);
    k_agg2<<<NN / 4, 256, 0, stream>>>(row_off, rec, aS2, aD2, xh2, b2v, Wfc, bfc,
                                       consts, out);
}